// Round 7
// baseline (820.414 us; speedup 1.0000x reference)
//
#include <hip/hip_runtime.h>
#include <hip/hip_bf16.h>
#include <stdint.h>
#include <type_traits>

// Problem constants: B=256, T=512, D=300, H=128, 4H=512, C=6
#define NB 256
#define NT 512
#define ND 300
#define NH 128
#define NG 512
#define NC 6

typedef __attribute__((ext_vector_type(8))) short short8;
typedef __attribute__((ext_vector_type(4))) float f32x4;

static __device__ __forceinline__ float bf2f(unsigned int u) {
  return __builtin_bit_cast(float, (u & 0xffffu) << 16);
}
static __device__ __forceinline__ unsigned short f2bf(float f) {
  return __builtin_bit_cast(unsigned short, __float2bfloat16(f));
}
static __device__ __forceinline__ unsigned int packbf(float a, float b) {
  return (unsigned int)f2bf(a) | ((unsigned int)f2bf(b) << 16);
}
static __device__ __forceinline__ float ld1(const unsigned short* p) { return bf2f(*p); }
static __device__ __forceinline__ float ld1(const float* p) { return *p; }
static __device__ __forceinline__ void st1(unsigned short* p, float v) { *p = f2bf(v); }
static __device__ __forceinline__ void st1(float* p, float v) { *p = v; }

static __device__ __forceinline__ float sigmoid_fast(float x) {
  return __builtin_amdgcn_rcpf(1.f + __expf(-x));
}
static __device__ __forceinline__ float tanh_fast(float x) {
  return 1.f - 2.f * __builtin_amdgcn_rcpf(__expf(2.f * x) + 1.f);
}

// Barrier that does NOT drain vmcnt: LDS ordering only (T4 idiom).
#define BARRIER_LGKM() asm volatile("s_waitcnt lgkmcnt(0)\n\ts_barrier" ::: "memory")

// ---- staging loads: 4 K-elems -> 2 packed bf16 pairs ------------------------
static __device__ __forceinline__ uint2 load4bf_fast(const unsigned short* row, int k) {
  return *(const uint2*)(row + k);
}
static __device__ __forceinline__ uint2 load4bf_fast(const float* row, int k) {
  float4 f = *(const float4*)(row + k);
  uint2 v;
  v.x = packbf(f.x, f.y);
  v.y = packbf(f.z, f.w);
  return v;
}
static __device__ __forceinline__ uint2 load4bf(const unsigned short* row, int k, int lim) {
  if (k + 3 < lim) return load4bf_fast(row, k);
  unsigned int e0 = (k + 0 < lim) ? row[k + 0] : 0;
  unsigned int e1 = (k + 1 < lim) ? row[k + 1] : 0;
  unsigned int e2 = (k + 2 < lim) ? row[k + 2] : 0;
  unsigned int e3 = (k + 3 < lim) ? row[k + 3] : 0;
  uint2 v;
  v.x = e0 | (e1 << 16);
  v.y = e2 | (e3 << 16);
  return v;
}
static __device__ __forceinline__ uint2 load4bf(const float* row, int k, int lim) {
  if (k + 3 < lim) return load4bf_fast(row, k);
  float f0 = (k + 0 < lim) ? row[k + 0] : 0.f;
  float f1 = (k + 1 < lim) ? row[k + 1] : 0.f;
  float f2 = (k + 2 < lim) ? row[k + 2] : 0.f;
  float f3 = (k + 3 < lim) ? row[k + 3] : 0.f;
  uint2 v;
  v.x = packbf(f0, f1);
  v.y = packbf(f2, f3);
  return v;
}

// ---------------------------------------------------------------------------
// Per-block dtype self-detect (0 = bf16 inputs, 1 = fp32 inputs).
// ---------------------------------------------------------------------------
static __device__ __forceinline__ int block_detect(const unsigned short* __restrict__ X,
                                                   int* cnt) {
  const int tid = threadIdx.x;
  const int nthr = blockDim.x;
  if (tid == 0) *cnt = 0;
  __syncthreads();
  int c = 0;
  for (int i = tid; i < 512; i += nthr) {
    unsigned int u = X[i];
    unsigned int e = (u >> 7) & 0xffu;
    if (u == 0u || (e >= 97u && e <= 157u)) c++;
  }
  if (c) atomicAdd(cnt, c);
  __syncthreads();
  return (*cnt >= 448) ? 0 : 1;
}

// ---------------------------------------------------------------------------
// gx producer tile: 64 t-rows x all 512 gates for one batch window.
// (unchanged from round 6 -- measured component, ~160us aggregate)
// ---------------------------------------------------------------------------
template <typename XT, typename GXT>
static __device__ __forceinline__ void gx_prod(
    const XT* __restrict__ X, const XT* __restrict__ Wih,
    const XT* __restrict__ bih, const XT* __restrict__ bhh,
    int b, int t0, int len, GXT* __restrict__ gxrow, unsigned short* smem) {
  auto As = reinterpret_cast<unsigned short(*)[64][40]>(smem);           // [10][64][40]
  auto Bs = reinterpret_cast<unsigned short(*)[128][40]>(smem + 25600);  // [2][128][40]

  const int tid = threadIdx.x;
  const int lane = tid & 63;
  const int wave = tid >> 6;
  const int wt = wave & 1;   // t-strip of 32
  const int wn4 = wave >> 1; // n-strip of 32 (within 128-col pass)
  const int lq = lane >> 4;
  const int lr = lane & 15;

  // ---- stage A (x): 64 rows x 320 k, once. 8 threads/row -----------------
  const int rA = tid >> 3;
  const int cA = (tid & 7) << 2;
  const XT* xrow = X + ((size_t)b * NT + t0 + rA) * ND;
  {
    uint2 a[10];
#pragma unroll
    for (int kc = 0; kc < 9; ++kc) a[kc] = load4bf_fast(xrow, kc * 32 + cA);
    a[9] = load4bf(xrow, 288 + cA, ND);
#pragma unroll
    for (int kc = 0; kc < 10; ++kc) *(uint2*)&As[kc][rA][cA] = a[kc];
  }

  // ---- W stream: 4 threads/row, 8 k each ---------------------------------
  const int rb = tid >> 2;
  const int kqo = (tid & 3) << 3;
  uint2 bv[3][2];
  {
    const XT* wb = Wih + (size_t)rb * ND;  // pass 0
#pragma unroll
    for (int s3 = 0; s3 < 3; ++s3) {
      bv[s3][0] = load4bf_fast(wb, s3 * 32 + kqo);
      bv[s3][1] = load4bf_fast(wb, s3 * 32 + kqo + 4);
    }
  }

  for (int nt = 0; nt < 4; ++nt) {
    const int n0 = nt << 7;
    const XT* wb = Wih + (size_t)(n0 + rb) * ND;

    f32x4 acc[2][2];
#pragma unroll
    for (int i = 0; i < 2; ++i)
#pragma unroll
      for (int j = 0; j < 2; ++j) {
        f32x4 z = {0.f, 0.f, 0.f, 0.f};
        acc[i][j] = z;
      }

    *(uint2*)&Bs[0][rb][kqo] = bv[0][0];
    *(uint2*)&Bs[0][rb][kqo + 4] = bv[0][1];
    BARRIER_LGKM();

#pragma unroll
    for (int kc = 0; kc < 10; ++kc) {
      const int bi = kc & 1;
      if (kc < 9) {
        *(uint2*)&Bs[bi ^ 1][rb][kqo] = bv[(kc + 1) % 3][0];
        *(uint2*)&Bs[bi ^ 1][rb][kqo + 4] = bv[(kc + 1) % 3][1];
      }
      if (kc < 7) {
        const int kn = (kc + 3) * 32 + kqo;
        if (kc < 6) {
          bv[kc % 3][0] = load4bf_fast(wb, kn);
          bv[kc % 3][1] = load4bf_fast(wb, kn + 4);
        } else {  // chunk 9: 288..319 masked at 300
          bv[kc % 3][0] = load4bf(wb, kn, ND);
          bv[kc % 3][1] = load4bf(wb, kn + 4, ND);
        }
      }

      short8 wF[2], aX[2];
#pragma unroll
      for (int tn = 0; tn < 2; ++tn)
        wF[tn] = *(const short8*)&Bs[bi][wn4 * 32 + tn * 16 + lr][lq * 8];
#pragma unroll
      for (int tt = 0; tt < 2; ++tt)
        aX[tt] = *(const short8*)&As[kc][wt * 32 + tt * 16 + lr][lq * 8];
#pragma unroll
      for (int tt = 0; tt < 2; ++tt)
#pragma unroll
        for (int tn = 0; tn < 2; ++tn)
          acc[tt][tn] =
              __builtin_amdgcn_mfma_f32_16x16x32_bf16(wF[tn], aX[tt], acc[tt][tn], 0, 0, 0);
      BARRIER_LGKM();
    }

    if (nt < 3) {
      const XT* wb2 = Wih + (size_t)((nt + 1) * 128 + rb) * ND;
#pragma unroll
      for (int s3 = 0; s3 < 3; ++s3) {
        bv[s3][0] = load4bf_fast(wb2, s3 * 32 + kqo);
        bv[s3][1] = load4bf_fast(wb2, s3 * 32 + kqo + 4);
      }
    }

    // Epilogue: D row (lq*4+rg) = gate col n; D col (lr) = t row.
    f32x4 bias4[2];
#pragma unroll
    for (int tn = 0; tn < 2; ++tn) {
      const int n = n0 + wn4 * 32 + tn * 16 + lq * 4;
#pragma unroll
      for (int rg = 0; rg < 4; ++rg) bias4[tn][rg] = ld1(bih + n + rg) + ld1(bhh + n + rg);
    }
#pragma unroll
    for (int tt = 0; tt < 2; ++tt) {
      const int trow = wt * 32 + tt * 16 + lr;
      if (t0 + trow < len) {
#pragma unroll
        for (int tn = 0; tn < 2; ++tn) {
          const int n = n0 + wn4 * 32 + tn * 16 + lq * 4;
          f32x4 o = acc[tt][tn] + bias4[tn];
          if constexpr (std::is_same_v<GXT, float>) {
            *(f32x4*)(gxrow + (size_t)trow * NG + n) = o;
          } else {
            uint2 v;
            v.x = packbf(o[0], o[1]);
            v.y = packbf(o[2], o[3]);
            *(uint2*)(gxrow + (size_t)trow * NG + n) = v;
          }
        }
      }
    }
  }
}

// ---------------------------------------------------------------------------
// One LSTM *phase* (no barrier): round-2 chained MFMA step, parameterized by
// per-batch state (hpk buffer, gx pointer, h/c registers, prefetch slot).
// Two phases (independent batches) share one barrier -- B's issue fills A's
// latency shadow (MFMA chain, VALU gate chain, LDS round-trip), and the
// barrier count per recurrence-step halves.
// ---------------------------------------------------------------------------
#define REC_PHASE(S, PAR, GC, CAP, HPKB, GP, HC, CC)                                 \
  {                                                                                  \
    short8 bfr[4];                                                                   \
    const unsigned short* hrow = (HPKB)[(PAR)];                                      \
    _Pragma("unroll") for (int c = 0; c < 4; ++c)                                    \
        bfr[c] = *(const short8*)&hrow[c * 32 + q * 8];                              \
    f32x4 acc[4];                                                                    \
    _Pragma("unroll") for (int g = 0; g < 4; ++g) {                                  \
      f32x4 z = {0.f, 0.f, 0.f, 0.f};                                                \
      acc[g] = z;                                                                    \
      _Pragma("unroll") for (int c = 0; c < 4; ++c)                                  \
          acc[g] = __builtin_amdgcn_mfma_f32_16x16x32_bf16(afr[g][c], bfr[c],        \
                                                           acc[g], 0, 0, 0);         \
    }                                                                                \
    float pre[4];                                                                    \
    _Pragma("unroll") for (int g = 0; g < 4; ++g) {                                  \
      const float t0v = (r & 1) ? acc[g][1] : acc[g][0];                             \
      const float t1v = (r & 1) ? acc[g][3] : acc[g][2];                             \
      pre[g] = ((r & 2) ? t1v : t0v) + GC[g];                                        \
    }                                                                                \
    {                                                                                \
      int idx_ = (S) + 2;                                                            \
      if (idx_ > (CAP)) idx_ = (CAP);                                                \
      _Pragma("unroll") for (int g = 0; g < 4; ++g)                                  \
          GC[g] = ld1((GP) + (size_t)idx_ * NG + g * NH);                            \
    }                                                                                \
    const float ig = sigmoid_fast(pre[0]);                                           \
    const float fg = sigmoid_fast(pre[1]);                                           \
    const float gg = tanh_fast(pre[2]);                                              \
    const float og = sigmoid_fast(pre[3]);                                           \
    CC = fmaf(fg, CC, ig * gg);                                                      \
    HC = og * tanh_fast(CC);                                                         \
    if (m < 4) (HPKB)[(PAR) ^ 1][u] = f2bf(HC);                                      \
  }

// ---------------------------------------------------------------------------
// rec A-fragment load: afr[g][c] = W_hh[g*128+w8*16+m][c*32+q*8..+8]
// ---------------------------------------------------------------------------
template <typename XT>
static __device__ __forceinline__ void load_afr(const XT* __restrict__ Whh, int w8,
                                                int q, int m, short8 afr[4][4]) {
#pragma unroll
  for (int g = 0; g < 4; ++g) {
    const int row = g * NH + w8 * 16 + m;
    if constexpr (std::is_same_v<XT, unsigned short>) {
#pragma unroll
      for (int c = 0; c < 4; ++c)
        afr[g][c] = *(const short8*)(Whh + (size_t)row * NH + c * 32 + q * 8);
    } else {
#pragma unroll
      for (int c = 0; c < 4; ++c) {
        const float* p = Whh + (size_t)row * NH + c * 32 + q * 8;
        float4 f0 = *(const float4*)p;
        float4 f1 = *(const float4*)(p + 4);
        union { unsigned int uu[4]; short8 s; } cv2;
        cv2.uu[0] = packbf(f0.x, f0.y);
        cv2.uu[1] = packbf(f0.z, f0.w);
        cv2.uu[2] = packbf(f1.x, f1.y);
        cv2.uu[3] = packbf(f1.z, f1.w);
        afr[g][c] = cv2.s;
      }
    }
  }
}

// ---------------------------------------------------------------------------
// Phase 2 body: TWO batches' recurrences interleaved per block. Shared
// W_hh fragments; phases A/B at the same parity share one barrier. All
// phase conditions (nsteps0/nsteps1) are block-uniform -> no divergent
// barrier. Per-batch math identical to round 2 (same MFMA order/gate math).
// ---------------------------------------------------------------------------
template <typename XT, typename GXT>
static __device__ __forceinline__ void rec_body2(
    const GXT* __restrict__ gx, const XT* __restrict__ Whh,
    const XT* __restrict__ fcw, const XT* __restrict__ fcb,
    const int* __restrict__ lengths, XT* __restrict__ out,
    float* __restrict__ hstate, float* __restrict__ cstate,
    int b_base, int t_base, int Tc, int NBc,
    unsigned short (*hpk)[2][NH], float (*hf)[NH]) {
  const int bc0 = blockIdx.x * 2;
  const bool hasB = (bc0 + 1 < NBc);
  const int bc1 = hasB ? bc0 + 1 : bc0;
  const int b0 = b_base + bc0;
  const int b1 = b_base + bc1;

  int len0 = lengths[b0];
  if (len0 > NT) len0 = NT;
  if (len0 < 0) len0 = 0;
  int len1 = lengths[b1];
  if (len1 > NT) len1 = NT;
  if (len1 < 0) len1 = 0;

  const bool first = (t_base == 0);
  const bool last = (t_base + Tc >= NT);
  int tend0 = (len0 < t_base + Tc) ? len0 : (t_base + Tc);
  int tend1 = (len1 < t_base + Tc) ? len1 : (t_base + Tc);
  int nsteps0 = tend0 - t_base;
  if (nsteps0 < 0) nsteps0 = 0;
  int nsteps1 = hasB ? (tend1 - t_base) : 0;
  if (nsteps1 < 0) nsteps1 = 0;
  if (!last && nsteps0 <= 0 && nsteps1 <= 0) return;  // uniform; state untouched

  const int tid = threadIdx.x;
  const int w8 = tid >> 6;
  const int l = tid & 63;
  const int q = l >> 4;
  const int m = l & 15;
  const int u0 = w8 * 16 + q * 4;
  const int r = m & 3;
  const int u = u0 + r;

  short8 afr[4][4];
  load_afr<XT>(Whh, w8, q, m, afr);

  float hcur0 = 0.f, ccur0 = 0.f, hcur1 = 0.f, ccur1 = 0.f;
  if (!first) {
    hcur0 = hstate[(size_t)bc0 * NH + u];
    ccur0 = cstate[(size_t)bc0 * NH + u];
    hcur1 = hstate[(size_t)bc1 * NH + u];
    ccur1 = cstate[(size_t)bc1 * NH + u];
  }
  if (m < 4) {
    hpk[0][0][u] = f2bf(hcur0);
    hpk[1][0][u] = f2bf(hcur1);
  }
  __syncthreads();

  const GXT* gp0 = gx + (size_t)bc0 * Tc * NG + u;
  const GXT* gp1 = gx + (size_t)bc1 * Tc * NG + u;
  const int cap0 = (nsteps0 > 0) ? nsteps0 - 1 : 0;
  const int cap1 = (nsteps1 > 0) ? nsteps1 - 1 : 0;

  // static-parity prefetch slots per batch
  float gsA0[4], gsA1[4], gsB0[4], gsB1[4];
  {
    const int i1a = (1 < cap0) ? 1 : cap0;
    const int i1b = (1 < cap1) ? 1 : cap1;
#pragma unroll
    for (int g = 0; g < 4; ++g) {
      gsA0[g] = ld1(gp0 + g * NH);
      gsA1[g] = ld1(gp0 + (size_t)i1a * NG + g * NH);
      gsB0[g] = ld1(gp1 + g * NH);
      gsB1[g] = ld1(gp1 + (size_t)i1b * NG + g * NH);
    }
  }

  const int smax = (nsteps0 > nsteps1) ? nsteps0 : nsteps1;
  int s = 0;
  for (; s + 1 < smax; s += 2) {
    if (s < nsteps0) REC_PHASE(s, 0, gsA0, cap0, hpk[0], gp0, hcur0, ccur0);
    if (hasB && s < nsteps1) REC_PHASE(s, 0, gsB0, cap1, hpk[1], gp1, hcur1, ccur1);
    BARRIER_LGKM();
    if (s + 1 < nsteps0) REC_PHASE(s + 1, 1, gsA1, cap0, hpk[0], gp0, hcur0, ccur0);
    if (hasB && s + 1 < nsteps1) REC_PHASE(s + 1, 1, gsB1, cap1, hpk[1], gp1, hcur1, ccur1);
    BARRIER_LGKM();
  }
  if (s < smax) {
    if (s < nsteps0) REC_PHASE(s, 0, gsA0, cap0, hpk[0], gp0, hcur0, ccur0);
    if (hasB && s < nsteps1) REC_PHASE(s, 0, gsB0, cap1, hpk[1], gp1, hcur1, ccur1);
    BARRIER_LGKM();
  }

  if (!last) {
    if (m < 4) {
      hstate[(size_t)bc0 * NH + u] = hcur0;
      cstate[(size_t)bc0 * NH + u] = ccur0;
      if (hasB) {
        hstate[(size_t)bc1 * NH + u] = hcur1;
        cstate[(size_t)bc1 * NH + u] = ccur1;
      }
    }
  } else {
    if (m < 4) {
      hf[0][u] = hcur0;
      if (hasB) hf[1][u] = hcur1;
    }
    __syncthreads();
    if (tid < NC) {
      float acc = ld1(fcb + tid);
      const XT* wv = fcw + (size_t)tid * NH;
#pragma unroll
      for (int k = 0; k < NH; ++k) acc = fmaf(ld1(wv + k), hf[0][k], acc);
      st1(out + (size_t)b0 * NC + tid, acc);
    } else if (hasB && tid >= 64 && tid < 64 + NC) {
      const int cc = tid - 64;
      float acc = ld1(fcb + cc);
      const XT* wv = fcw + (size_t)cc * NH;
#pragma unroll
      for (int k = 0; k < NH; ++k) acc = fmaf(ld1(wv + k), hf[1][k], acc);
      st1(out + (size_t)b1 * NC + cc, acc);
    }
  }
}

// ---------------------------------------------------------------------------
// Runtime-dtype kernels (2 launches per invocation total).
// ---------------------------------------------------------------------------
template <typename GXT>
__global__ __launch_bounds__(512, 4) void gx_gemm_rt(const void* __restrict__ X,
                                                     const void* __restrict__ Wih,
                                                     const void* __restrict__ bih,
                                                     const void* __restrict__ bhh,
                                                     const int* __restrict__ lengths,
                                                     GXT* __restrict__ gx,
                                                     int b_base, int t_base, int Tc) {
  __shared__ int cnt;
  __shared__ __align__(16) unsigned short smem[35840];  // As 50K + Bs 20K
  const int isf32 = block_detect((const unsigned short*)X, &cnt);
  const int m0 = blockIdx.x << 6;
  const int bc = m0 / Tc;
  const int trel = m0 % Tc;
  const int b = b_base + bc;
  const int t0 = t_base + trel;
  int len = lengths[b];
  if (len > NT) len = NT;
  if (t0 >= len) return;  // block-uniform
  GXT* gxrow = gx + (size_t)m0 * NG;
  if (isf32)
    gx_prod<float, GXT>((const float*)X, (const float*)Wih, (const float*)bih,
                        (const float*)bhh, b, t0, len, gxrow, smem);
  else
    gx_prod<unsigned short, GXT>((const unsigned short*)X, (const unsigned short*)Wih,
                                 (const unsigned short*)bih, (const unsigned short*)bhh,
                                 b, t0, len, gxrow, smem);
}

template <typename GXT>
__global__ __launch_bounds__(512)
__attribute__((amdgpu_waves_per_eu(2, 2)))
void lstm_rec_rt(const void* __restrict__ X, const GXT* __restrict__ gx,
                 const void* __restrict__ Whh, const void* __restrict__ fcw,
                 const void* __restrict__ fcb, const int* __restrict__ lengths,
                 void* __restrict__ out, float* __restrict__ hstate,
                 float* __restrict__ cstate, int b_base, int t_base, int Tc,
                 int NBc) {
  __shared__ int cnt;
  __shared__ __align__(16) unsigned short hpk[2][2][NH];  // [batch][parity]
  __shared__ __align__(16) float hf[2][NH];
  const int isf32 = block_detect((const unsigned short*)X, &cnt);
  if (isf32)
    rec_body2<float, GXT>(gx, (const float*)Whh, (const float*)fcw, (const float*)fcb,
                          lengths, (float*)out, hstate, cstate, b_base, t_base, Tc,
                          NBc, hpk, hf);
  else
    rec_body2<unsigned short, GXT>(gx, (const unsigned short*)Whh,
                                   (const unsigned short*)fcw,
                                   (const unsigned short*)fcb, lengths,
                                   (unsigned short*)out, hstate, cstate, b_base,
                                   t_base, Tc, NBc, hpk, hf);
}

// ---------------------------------------------------------------------------
template <typename GXT>
static void run_all(void* const* d_in, void* d_out, GXT* gx, float* hstate,
                    float* cstate, int NBc, int Tc, hipStream_t stream) {
  const int* lengths = (const int*)d_in[7];
  for (int bb = 0; bb < NB; bb += NBc) {
    for (int tb = 0; tb < NT; tb += Tc) {
      gx_gemm_rt<GXT><<<dim3((NBc * Tc) / 64), dim3(512), 0, stream>>>(
          d_in[0], d_in[1], d_in[3], d_in[4], lengths, gx, bb, tb, Tc);
      lstm_rec_rt<GXT><<<dim3((NBc + 1) / 2), dim3(512), 0, stream>>>(
          d_in[0], gx, d_in[2], d_in[5], d_in[6], lengths, d_out, hstate, cstate,
          bb, tb, Tc, NBc);
    }
  }
}

extern "C" void kernel_launch(void* const* d_in, const int* in_sizes, int n_in,
                              void* d_out, int out_size, void* d_ws, size_t ws_size,
                              hipStream_t stream) {
  const size_t full_f32 = (size_t)NB * NT * NG * sizeof(float);
  const size_t full_bf16 = (size_t)NB * NT * NG * 2;
  const size_t base = 512;

  int NBc, Tc;
  char* gx_raw;
  float* hstate = (float*)((char*)d_ws + base);
  bool gx_is_f32;

  if (ws_size >= base + full_f32) {
    NBc = NB; Tc = NT; gx_is_f32 = true;
    gx_raw = (char*)d_ws + base;  // hstate unused in the single-chunk path
  } else if (ws_size >= base + full_bf16) {
    NBc = NB; Tc = NT; gx_is_f32 = false;
    gx_raw = (char*)d_ws + base;
  } else {
    Tc = 128; gx_is_f32 = false;
    NBc = 1;
    for (int cand : {64, 16, 4}) {
      size_t need = base + (size_t)cand * NH * 2 * sizeof(float) + (size_t)cand * Tc * NG * 2;
      if (ws_size >= need) { NBc = cand; break; }
    }
    gx_raw = (char*)d_ws + base + (size_t)NBc * NH * 2 * sizeof(float);
  }
  float* cstate = hstate + (size_t)NBc * NH;

  if (gx_is_f32) {
    run_all<float>(d_in, d_out, (float*)gx_raw, hstate, cstate, NBc, Tc, stream);
  } else {
    run_all<unsigned short>(d_in, d_out, (unsigned short*)gx_raw, hstate, cstate,
                            NBc, Tc, stream);
  }
}

// Round 8
// 746.873 us; speedup vs baseline: 1.0985x; 1.0985x over previous
//
#include <hip/hip_runtime.h>
#include <hip/hip_bf16.h>
#include <stdint.h>
#include <type_traits>

// Problem constants: B=256, T=512, D=300, H=128, 4H=512, C=6
#define NB 256
#define NT 512
#define ND 300
#define NH 128
#define NG 512
#define NC 6

typedef __attribute__((ext_vector_type(8))) short short8;
typedef __attribute__((ext_vector_type(4))) float f32x4;

static __device__ __forceinline__ float bf2f(unsigned int u) {
  return __builtin_bit_cast(float, (u & 0xffffu) << 16);
}
static __device__ __forceinline__ unsigned short f2bf(float f) {
  return __builtin_bit_cast(unsigned short, __float2bfloat16(f));
}
static __device__ __forceinline__ unsigned int packbf(float a, float b) {
  return (unsigned int)f2bf(a) | ((unsigned int)f2bf(b) << 16);
}
static __device__ __forceinline__ float ld1(const unsigned short* p) { return bf2f(*p); }
static __device__ __forceinline__ float ld1(const float* p) { return *p; }
static __device__ __forceinline__ void st1(unsigned short* p, float v) { *p = f2bf(v); }
static __device__ __forceinline__ void st1(float* p, float v) { *p = v; }

static __device__ __forceinline__ float sigmoid_fast(float x) {
  return __builtin_amdgcn_rcpf(1.f + __expf(-x));
}
static __device__ __forceinline__ float tanh_fast(float x) {
  return 1.f - 2.f * __builtin_amdgcn_rcpf(__expf(2.f * x) + 1.f);
}

// Barrier that does NOT drain vmcnt: LDS ordering only (T4 idiom).
#define BARRIER_LGKM() asm volatile("s_waitcnt lgkmcnt(0)\n\ts_barrier" ::: "memory")

// ---- staging loads: 4 K-elems -> 2 packed bf16 pairs ------------------------
static __device__ __forceinline__ uint2 load4bf_fast(const unsigned short* row, int k) {
  return *(const uint2*)(row + k);
}
static __device__ __forceinline__ uint2 load4bf_fast(const float* row, int k) {
  float4 f = *(const float4*)(row + k);
  uint2 v;
  v.x = packbf(f.x, f.y);
  v.y = packbf(f.z, f.w);
  return v;
}
static __device__ __forceinline__ uint2 load4bf(const unsigned short* row, int k, int lim) {
  if (k + 3 < lim) return load4bf_fast(row, k);
  unsigned int e0 = (k + 0 < lim) ? row[k + 0] : 0;
  unsigned int e1 = (k + 1 < lim) ? row[k + 1] : 0;
  unsigned int e2 = (k + 2 < lim) ? row[k + 2] : 0;
  unsigned int e3 = (k + 3 < lim) ? row[k + 3] : 0;
  uint2 v;
  v.x = e0 | (e1 << 16);
  v.y = e2 | (e3 << 16);
  return v;
}
static __device__ __forceinline__ uint2 load4bf(const float* row, int k, int lim) {
  if (k + 3 < lim) return load4bf_fast(row, k);
  float f0 = (k + 0 < lim) ? row[k + 0] : 0.f;
  float f1 = (k + 1 < lim) ? row[k + 1] : 0.f;
  float f2 = (k + 2 < lim) ? row[k + 2] : 0.f;
  float f3 = (k + 3 < lim) ? row[k + 3] : 0.f;
  uint2 v;
  v.x = packbf(f0, f1);
  v.y = packbf(f2, f3);
  return v;
}

// ---- W fragment loaders: 8 contiguous K-elems of one W row -> short8 --------
// bf16: row*600B + k*2B is 8B-aligned (k%8==0) -> 2x dwordx2.
// f32:  row*1200B + k*4B is 16B-aligned -> 2x float4 + pack.
static __device__ __forceinline__ short8 wfrag_fast(const unsigned short* W, int row, int k) {
  const unsigned short* p = W + (size_t)row * ND + k;
  union { uint2 u[2]; short8 s; } cv;
  cv.u[0] = *(const uint2*)p;
  cv.u[1] = *(const uint2*)(p + 4);
  return cv.s;
}
static __device__ __forceinline__ short8 wfrag_fast(const float* W, int row, int k) {
  const float* p = W + (size_t)row * ND + k;
  float4 f0 = *(const float4*)p;
  float4 f1 = *(const float4*)(p + 4);
  union { unsigned int u[4]; short8 s; } cv;
  cv.u[0] = packbf(f0.x, f0.y);
  cv.u[1] = packbf(f0.z, f0.w);
  cv.u[2] = packbf(f1.x, f1.y);
  cv.u[3] = packbf(f1.z, f1.w);
  return cv.s;
}
template <typename XT>
static __device__ __forceinline__ short8 wfrag_masked(const XT* W, int row, int k) {
  const XT* p = W + (size_t)row * ND;
  union { uint2 u[2]; short8 s; } cv;
  cv.u[0] = load4bf(p, k, ND);
  cv.u[1] = load4bf(p, k + 4, ND);
  return cv.s;
}

// ---------------------------------------------------------------------------
// Per-block dtype self-detect (0 = bf16 inputs, 1 = fp32 inputs).
// ---------------------------------------------------------------------------
static __device__ __forceinline__ int block_detect(const unsigned short* __restrict__ X,
                                                   int* cnt) {
  const int tid = threadIdx.x;
  const int nthr = blockDim.x;
  if (tid == 0) *cnt = 0;
  __syncthreads();
  int c = 0;
  for (int i = tid; i < 512; i += nthr) {
    unsigned int u = X[i];
    unsigned int e = (u >> 7) & 0xffu;
    if (u == 0u || (e >= 97u && e <= 157u)) c++;
  }
  if (c) atomicAdd(cnt, c);
  __syncthreads();
  return (*cnt >= 448) ? 0 : 1;
}

// ---------------------------------------------------------------------------
// gx producer tile: 64 t-rows x all 512 gates for one batch window.
// THIS ROUND: W LDS staging ELIMINATED. Each lane's W fragment is 8
// contiguous elements of one W row -> loaded directly from global (W is
// 600 KB, L2-resident) into the MFMA A operand. As (x tile) staged once;
// ONE barrier per block (was 80: 4 passes x 10 chunks x 2). K-loop is
// barrier-free with a 3-slot register prefetch (distance 3 ~ 2 chunk
// bodies of L2-latency slack). LDS 70->50 KB -> 3 blocks/CU.
// MFMA operands: A = W frag (row = gate col), B = x frag -> D = [gate][t],
// f32x4 stores. Same products/order as round 6 -> identical numerics.
// ---------------------------------------------------------------------------
template <typename XT, typename GXT>
static __device__ __forceinline__ void gx_prod(
    const XT* __restrict__ X, const XT* __restrict__ Wih,
    const XT* __restrict__ bih, const XT* __restrict__ bhh,
    int b, int t0, int len, GXT* __restrict__ gxrow, unsigned short* smem) {
  auto As = reinterpret_cast<unsigned short(*)[64][40]>(smem);  // [10][64][40] 50KB

  const int tid = threadIdx.x;
  const int lane = tid & 63;
  const int wave = tid >> 6;
  const int wt = wave & 1;   // t-strip of 32
  const int wn4 = wave >> 1; // n-strip of 32 (within 128-col pass)
  const int lq = lane >> 4;
  const int lr = lane & 15;

  // ---- stage A (x): 64 rows x 320 k, once. 8 threads/row -----------------
  const int rA = tid >> 3;
  const int cA = (tid & 7) << 2;
  const XT* xrow = X + ((size_t)b * NT + t0 + rA) * ND;
  {
    uint2 a[10];
#pragma unroll
    for (int kc = 0; kc < 9; ++kc) a[kc] = load4bf_fast(xrow, kc * 32 + cA);
    a[9] = load4bf(xrow, 288 + cA, ND);
#pragma unroll
    for (int kc = 0; kc < 10; ++kc) *(uint2*)&As[kc][rA][cA] = a[kc];
  }
  BARRIER_LGKM();  // publish As; no further barriers in this kernel

  // W fragment rows for this lane: pass nt, tile tn -> nt*128 + wn4*32 + tn*16 + lr
  const int wr = wn4 * 32 + lr;

  // 3-slot register prefetch: chunk kc of the current pass lives in wv[kc%3].
  short8 wv[3][2];
#pragma unroll
  for (int s3 = 0; s3 < 3; ++s3)
#pragma unroll
    for (int tn = 0; tn < 2; ++tn)
      wv[s3][tn] = wfrag_fast(Wih, wr + tn * 16, s3 * 32 + lq * 8);

  for (int nt = 0; nt < 4; ++nt) {
    const int n0 = nt << 7;

    f32x4 acc[2][2];
#pragma unroll
    for (int i = 0; i < 2; ++i)
#pragma unroll
      for (int j = 0; j < 2; ++j) {
        f32x4 z = {0.f, 0.f, 0.f, 0.f};
        acc[i][j] = z;
      }

#pragma unroll
    for (int kc = 0; kc < 10; ++kc) {
      short8 aX[2];
#pragma unroll
      for (int tt = 0; tt < 2; ++tt)
        aX[tt] = *(const short8*)&As[kc][wt * 32 + tt * 16 + lr][lq * 8];
#pragma unroll
      for (int tt = 0; tt < 2; ++tt)
#pragma unroll
        for (int tn = 0; tn < 2; ++tn)
          acc[tt][tn] = __builtin_amdgcn_mfma_f32_16x16x32_bf16(wv[kc % 3][tn], aX[tt],
                                                                acc[tt][tn], 0, 0, 0);
      // prefetch chunk kc+3 of this pass into the slot just consumed
      if (kc < 7) {
        const int kn = (kc + 3) * 32 + lq * 8;
        if (kc < 6) {
#pragma unroll
          for (int tn = 0; tn < 2; ++tn)
            wv[kc % 3][tn] = wfrag_fast(Wih, n0 + wr + tn * 16, kn);
        } else {  // chunk 9: k 288..319 masked at 300
#pragma unroll
          for (int tn = 0; tn < 2; ++tn)
            wv[kc % 3][tn] = wfrag_masked(Wih, n0 + wr + tn * 16, kn);
        }
      }
    }

    // preload next pass's chunks 0-2 (epilogue hides the latency)
    if (nt < 3) {
      const int n0n = (nt + 1) << 7;
#pragma unroll
      for (int s3 = 0; s3 < 3; ++s3)
#pragma unroll
        for (int tn = 0; tn < 2; ++tn)
          wv[s3][tn] = wfrag_fast(Wih, n0n + wr + tn * 16, s3 * 32 + lq * 8);
    }

    // Epilogue: D row (lq*4+rg) = gate col n; D col (lr) = t row.
    f32x4 bias4[2];
#pragma unroll
    for (int tn = 0; tn < 2; ++tn) {
      const int n = n0 + wn4 * 32 + tn * 16 + lq * 4;
#pragma unroll
      for (int rg = 0; rg < 4; ++rg) bias4[tn][rg] = ld1(bih + n + rg) + ld1(bhh + n + rg);
    }
#pragma unroll
    for (int tt = 0; tt < 2; ++tt) {
      const int trow = wt * 32 + tt * 16 + lr;
      if (t0 + trow < len) {
#pragma unroll
        for (int tn = 0; tn < 2; ++tn) {
          const int n = n0 + wn4 * 32 + tn * 16 + lq * 4;
          f32x4 o = acc[tt][tn] + bias4[tn];
          if constexpr (std::is_same_v<GXT, float>) {
            *(f32x4*)(gxrow + (size_t)trow * NG + n) = o;
          } else {
            uint2 v;
            v.x = packbf(o[0], o[1]);
            v.y = packbf(o[2], o[3]);
            *(uint2*)(gxrow + (size_t)trow * NG + n) = v;
          }
        }
      }
    }
  }
}

// ---------------------------------------------------------------------------
// One LSTM step -- EXACT round-2/6 structure (chained MFMA accumulation;
// tree-add and 2-batch interleave both regressed -- rounds 4 and 7).
// PAR compile-time 0/1; GC reloaded with step S+2's gx row, clamped to CAP.
// ---------------------------------------------------------------------------
#define REC_STEP(S, PAR, GC, CAP)                                                    \
  {                                                                                  \
    short8 bfr[4];                                                                   \
    const unsigned short* hrow = hpk[(PAR)];                                         \
    _Pragma("unroll") for (int c = 0; c < 4; ++c)                                    \
        bfr[c] = *(const short8*)&hrow[c * 32 + q * 8];                              \
    f32x4 acc[4];                                                                    \
    _Pragma("unroll") for (int g = 0; g < 4; ++g) {                                  \
      f32x4 z = {0.f, 0.f, 0.f, 0.f};                                                \
      acc[g] = z;                                                                    \
      _Pragma("unroll") for (int c = 0; c < 4; ++c)                                  \
          acc[g] = __builtin_amdgcn_mfma_f32_16x16x32_bf16(afr[g][c], bfr[c],        \
                                                           acc[g], 0, 0, 0);         \
    }                                                                                \
    float pre[4];                                                                    \
    _Pragma("unroll") for (int g = 0; g < 4; ++g) {                                  \
      const float t0v = (r & 1) ? acc[g][1] : acc[g][0];                             \
      const float t1v = (r & 1) ? acc[g][3] : acc[g][2];                             \
      pre[g] = ((r & 2) ? t1v : t0v) + GC[g];                                        \
    }                                                                                \
    {                                                                                \
      int idx_ = (S) + 2;                                                            \
      if (idx_ > (CAP)) idx_ = (CAP);                                                \
      _Pragma("unroll") for (int g = 0; g < 4; ++g)                                  \
          GC[g] = ld1(gp + (size_t)idx_ * NG + g * NH);                              \
    }                                                                                \
    const float ig = sigmoid_fast(pre[0]);                                           \
    const float fg = sigmoid_fast(pre[1]);                                           \
    const float gg = tanh_fast(pre[2]);                                              \
    const float og = sigmoid_fast(pre[3]);                                           \
    ccur = fmaf(fg, ccur, ig * gg);                                                  \
    hcur = og * tanh_fast(ccur);                                                     \
    if (m < 4) hpk[(PAR) ^ 1][u] = f2bf(hcur);                                       \
    BARRIER_LGKM();                                                                  \
  }

// ---------------------------------------------------------------------------
// rec A-fragment load: afr[g][c] = W_hh[g*128+w8*16+m][c*32+q*8..+8]
// ---------------------------------------------------------------------------
template <typename XT>
static __device__ __forceinline__ void load_afr(const XT* __restrict__ Whh, int w8,
                                                int q, int m, short8 afr[4][4]) {
#pragma unroll
  for (int g = 0; g < 4; ++g) {
    const int row = g * NH + w8 * 16 + m;
    if constexpr (std::is_same_v<XT, unsigned short>) {
#pragma unroll
      for (int c = 0; c < 4; ++c)
        afr[g][c] = *(const short8*)(Whh + (size_t)row * NH + c * 32 + q * 8);
    } else {
#pragma unroll
      for (int c = 0; c < 4; ++c) {
        const float* p = Whh + (size_t)row * NH + c * 32 + q * 8;
        float4 f0 = *(const float4*)p;
        float4 f1 = *(const float4*)(p + 4);
        union { unsigned int uu[4]; short8 s; } cv2;
        cv2.uu[0] = packbf(f0.x, f0.y);
        cv2.uu[1] = packbf(f0.z, f0.w);
        cv2.uu[2] = packbf(f1.x, f1.y);
        cv2.uu[3] = packbf(f1.z, f1.w);
        afr[g][c] = cv2.s;
      }
    }
  }
}

// ---------------------------------------------------------------------------
// Phase 2 body: per-batch recurrence via MFMA matvec -- EXACT round-6
// structure (measured 276us): lgkm-only per-step barrier, static-parity gx
// prefetch slots (gs0/gs1, unroll-2), chained MFMA accumulation, 1 batch
// per block (256 blocks -- full-occupancy across CUs; round 7's 2-batch
// interleave halved CU usage and regressed).
// ---------------------------------------------------------------------------
template <typename XT, typename GXT>
static __device__ __forceinline__ void rec_body(
    const GXT* __restrict__ gx, const XT* __restrict__ Whh,
    const XT* __restrict__ fcw, const XT* __restrict__ fcb,
    const int* __restrict__ lengths, XT* __restrict__ out,
    float* __restrict__ hstate, float* __restrict__ cstate,
    int b_base, int t_base, int Tc,
    unsigned short (*hpk)[NH], float* hf) {
  const int bc = blockIdx.x;
  const int b = b_base + bc;
  int len = lengths[b];
  if (len > NT) len = NT;
  if (len < 0) len = 0;
  const bool first = (t_base == 0);
  const bool last = (t_base + Tc >= NT);
  const int tend = (len < t_base + Tc) ? len : (t_base + Tc);
  if (!last && tend <= t_base) return;
  int nsteps = tend - t_base;
  if (nsteps < 0) nsteps = 0;

  const int tid = threadIdx.x;
  const int w8 = tid >> 6;
  const int l = tid & 63;
  const int q = l >> 4;
  const int m = l & 15;
  const int u0 = w8 * 16 + q * 4;
  const int r = m & 3;
  const int u = u0 + r;

  short8 afr[4][4];
  load_afr<XT>(Whh, w8, q, m, afr);

  float hcur = 0.f, ccur = 0.f;
  if (!first) {
    hcur = hstate[(size_t)bc * NH + u];
    ccur = cstate[(size_t)bc * NH + u];
  }
  if (m < 4) hpk[0][u] = f2bf(hcur);
  __syncthreads();

  const GXT* gp = gx + (size_t)bc * Tc * NG + u;
  const int lastidx = (nsteps > 0) ? nsteps - 1 : 0;

  float gs0[4], gs1[4];
  {
    const int i1 = (1 < lastidx) ? 1 : lastidx;
#pragma unroll
    for (int g = 0; g < 4; ++g) {
      gs0[g] = ld1(gp + g * NH);
      gs1[g] = ld1(gp + (size_t)i1 * NG + g * NH);
    }
  }

  int s = 0;
  for (; s + 1 < nsteps; s += 2) {
    REC_STEP(s, 0, gs0, lastidx);
    REC_STEP(s + 1, 1, gs1, lastidx);
  }
  if (s < nsteps) {
    REC_STEP(s, 0, gs0, lastidx);
  }

  if (!last) {
    if (m < 4) {
      hstate[(size_t)bc * NH + u] = hcur;
      cstate[(size_t)bc * NH + u] = ccur;
    }
  } else {
    if (m < 4) hf[u] = hcur;
    __syncthreads();
    if (tid < NC) {
      float acc = ld1(fcb + tid);
      const XT* wv = fcw + (size_t)tid * NH;
#pragma unroll
      for (int k = 0; k < NH; ++k) acc = fmaf(ld1(wv + k), hf[k], acc);
      st1(out + (size_t)b * NC + tid, acc);
    }
  }
}

// ---------------------------------------------------------------------------
// Runtime-dtype kernels (2 launches per invocation total).
// ---------------------------------------------------------------------------
template <typename GXT>
__global__ __launch_bounds__(512, 4) void gx_gemm_rt(const void* __restrict__ X,
                                                     const void* __restrict__ Wih,
                                                     const void* __restrict__ bih,
                                                     const void* __restrict__ bhh,
                                                     const int* __restrict__ lengths,
                                                     GXT* __restrict__ gx,
                                                     int b_base, int t_base, int Tc) {
  __shared__ int cnt;
  __shared__ __align__(16) unsigned short smem[25600];  // As only, 50 KB
  const int isf32 = block_detect((const unsigned short*)X, &cnt);
  const int m0 = blockIdx.x << 6;
  const int bc = m0 / Tc;
  const int trel = m0 % Tc;
  const int b = b_base + bc;
  const int t0 = t_base + trel;
  int len = lengths[b];
  if (len > NT) len = NT;
  if (t0 >= len) return;  // block-uniform
  GXT* gxrow = gx + (size_t)m0 * NG;
  if (isf32)
    gx_prod<float, GXT>((const float*)X, (const float*)Wih, (const float*)bih,
                        (const float*)bhh, b, t0, len, gxrow, smem);
  else
    gx_prod<unsigned short, GXT>((const unsigned short*)X, (const unsigned short*)Wih,
                                 (const unsigned short*)bih, (const unsigned short*)bhh,
                                 b, t0, len, gxrow, smem);
}

template <typename GXT>
__global__ __launch_bounds__(512)
__attribute__((amdgpu_waves_per_eu(2, 2)))
void lstm_rec_rt(const void* __restrict__ X, const GXT* __restrict__ gx,
                 const void* __restrict__ Whh, const void* __restrict__ fcw,
                 const void* __restrict__ fcb, const int* __restrict__ lengths,
                 void* __restrict__ out, float* __restrict__ hstate,
                 float* __restrict__ cstate, int b_base, int t_base, int Tc) {
  __shared__ int cnt;
  __shared__ __align__(16) unsigned short hpk[2][NH];
  __shared__ __align__(16) float hf[NH];
  const int isf32 = block_detect((const unsigned short*)X, &cnt);
  if (isf32)
    rec_body<float, GXT>(gx, (const float*)Whh, (const float*)fcw, (const float*)fcb,
                         lengths, (float*)out, hstate, cstate, b_base, t_base, Tc,
                         hpk, hf);
  else
    rec_body<unsigned short, GXT>(gx, (const unsigned short*)Whh,
                                  (const unsigned short*)fcw,
                                  (const unsigned short*)fcb, lengths,
                                  (unsigned short*)out, hstate, cstate, b_base,
                                  t_base, Tc, hpk, hf);
}

// ---------------------------------------------------------------------------
template <typename GXT>
static void run_all(void* const* d_in, void* d_out, GXT* gx, float* hstate,
                    float* cstate, int NBc, int Tc, hipStream_t stream) {
  const int* lengths = (const int*)d_in[7];
  for (int bb = 0; bb < NB; bb += NBc) {
    for (int tb = 0; tb < NT; tb += Tc) {
      gx_gemm_rt<GXT><<<dim3((NBc * Tc) / 64), dim3(512), 0, stream>>>(
          d_in[0], d_in[1], d_in[3], d_in[4], lengths, gx, bb, tb, Tc);
      lstm_rec_rt<GXT><<<dim3(NBc), dim3(512), 0, stream>>>(
          d_in[0], gx, d_in[2], d_in[5], d_in[6], lengths, d_out, hstate, cstate,
          bb, tb, Tc);
    }
  }
}

extern "C" void kernel_launch(void* const* d_in, const int* in_sizes, int n_in,
                              void* d_out, int out_size, void* d_ws, size_t ws_size,
                              hipStream_t stream) {
  const size_t full_f32 = (size_t)NB * NT * NG * sizeof(float);
  const size_t full_bf16 = (size_t)NB * NT * NG * 2;
  const size_t base = 512;

  int NBc, Tc;
  char* gx_raw;
  float* hstate = (float*)((char*)d_ws + base);
  bool gx_is_f32;

  if (ws_size >= base + full_f32) {
    NBc = NB; Tc = NT; gx_is_f32 = true;
    gx_raw = (char*)d_ws + base;  // hstate unused in the single-chunk path
  } else if (ws_size >= base + full_bf16) {
    NBc = NB; Tc = NT; gx_is_f32 = false;
    gx_raw = (char*)d_ws + base;
  } else {
    Tc = 128; gx_is_f32 = false;
    NBc = 1;
    for (int cand : {64, 16, 4}) {
      size_t need = base + (size_t)cand * NH * 2 * sizeof(float) + (size_t)cand * Tc * NG * 2;
      if (ws_size >= need) { NBc = cand; break; }
    }
    gx_raw = (char*)d_ws + base + (size_t)NBc * NH * 2 * sizeof(float);
  }
  float* cstate = hstate + (size_t)NBc * NH;

  if (gx_is_f32) {
    run_all<float>(d_in, d_out, (float*)gx_raw, hstate, cstate, NBc, Tc, stream);
  } else {
    run_all<unsigned short>(d_in, d_out, (unsigned short*)gx_raw, hstate, cstate,
                            NBc, Tc, stream);
  }
}